// Round 1
// baseline (642.552 us; speedup 1.0000x reference)
//
#include <hip/hip_runtime.h>
#include <cstdint>
#include <cstddef>

#define SEQ 512
#define BATCH 256
#define IN_DIM 300
#define HID 256

typedef __attribute__((ext_vector_type(8))) short bf16x8;
typedef __attribute__((ext_vector_type(4))) float f32x4;

__device__ __forceinline__ unsigned short f2bf(float f) {
  union { float f; unsigned int u; } v; v.f = f;
  unsigned int u = v.u;
  return (unsigned short)((u + 0x7fffu + ((u >> 16) & 1u)) >> 16);  // RNE
}
__device__ __forceinline__ float bf2f(unsigned short s) {
  union { unsigned int u; float f; } v; v.u = ((unsigned int)s) << 16;
  return v.f;
}

// ---------------- kernel 0: W_ih fp32 -> bf16, padded [256][320] (zeros past 300)
__global__ __launch_bounds__(256) void conv_wih(const float* __restrict__ w,
                                                unsigned short* __restrict__ w_bf) {
  int idx = blockIdx.x * 256 + threadIdx.x;   // 0 .. 256*320-1
  int n = idx / 320, k = idx - n * 320;
  float v = (k < IN_DIM) ? w[n * IN_DIM + k] : 0.f;
  w_bf[idx] = f2bf(v);
}

// ---------------- kernel 1: xp[m][n] = sum_k x[m][k]*W_ih[n][k] + (b_ih+b_hh)[n], bf16 out
// M = SEQ*BATCH = 131072 (64/block), N = 256, K = 300 (10 chunks of 32, zero-padded)
__global__ __launch_bounds__(256) void gemm_xp(const float* __restrict__ x,
    const unsigned short* __restrict__ w_bf, const float* __restrict__ b_ih,
    const float* __restrict__ b_hh, unsigned short* __restrict__ xp)
{
  __shared__ unsigned short a_lds[64][40];    // +8 pad: bank-shift 4, 2-way max (free)
  __shared__ unsigned short w_lds[256][40];
  const int tid  = threadIdx.x;
  const int wave = tid >> 6;
  const int lane = tid & 63;
  const int l15  = lane & 15;
  const int quad = lane >> 4;
  const long m0 = (long)blockIdx.x * 64;

  f32x4 acc[4][4];
  #pragma unroll
  for (int mt = 0; mt < 4; ++mt)
    #pragma unroll
    for (int nt = 0; nt < 4; ++nt) acc[mt][nt] = (f32x4){0.f, 0.f, 0.f, 0.f};

  const int ar = tid >> 2;          // 0..63 row
  const int ac = (tid & 3) * 8;     // 0,8,16,24

  for (int kc = 0; kc < 10; ++kc) {
    const int k0 = kc * 32;
    // stage A: 64 rows x 32 k, fp32 -> bf16 (guard k<300; row stride 300 -> 8B aligned)
    {
      float v[8];
      const float* src = x + (size_t)(m0 + ar) * IN_DIM + (k0 + ac);
      if (k0 + ac + 8 <= IN_DIM) {
        float2 p0 = *(const float2*)(src + 0);
        float2 p1 = *(const float2*)(src + 2);
        float2 p2 = *(const float2*)(src + 4);
        float2 p3 = *(const float2*)(src + 6);
        v[0]=p0.x; v[1]=p0.y; v[2]=p1.x; v[3]=p1.y;
        v[4]=p2.x; v[5]=p2.y; v[6]=p3.x; v[7]=p3.y;
      } else {
        #pragma unroll
        for (int j = 0; j < 8; ++j) v[j] = (k0 + ac + j < IN_DIM) ? src[j] : 0.f;
      }
      union { unsigned short u[8]; bf16x8 vec; } tmp;
      #pragma unroll
      for (int j = 0; j < 8; ++j) tmp.u[j] = f2bf(v[j]);
      *(bf16x8*)&a_lds[ar][ac] = tmp.vec;
    }
    // stage W: 256 n x 32 k bf16 from padded w_bf
    #pragma unroll
    for (int i = 0; i < 8; ++i) {
      int e = tid + i * 256;          // 0..2047 uint2 elems
      int n = e >> 3;
      int kk = (e & 7) * 4;
      uint2 d = *(const uint2*)(w_bf + n * 320 + k0 + kk);
      *(uint2*)&w_lds[n][kk] = d;
    }
    __syncthreads();
    bf16x8 afr[4], bfr[4];
    #pragma unroll
    for (int mt = 0; mt < 4; ++mt)
      afr[mt] = *(const bf16x8*)&a_lds[mt*16 + l15][quad*8];
    #pragma unroll
    for (int nt = 0; nt < 4; ++nt)
      bfr[nt] = *(const bf16x8*)&w_lds[wave*64 + nt*16 + l15][quad*8];
    #pragma unroll
    for (int mt = 0; mt < 4; ++mt)
      #pragma unroll
      for (int nt = 0; nt < 4; ++nt)
        acc[mt][nt] = __builtin_amdgcn_mfma_f32_16x16x32_bf16(afr[mt], bfr[nt], acc[mt][nt], 0, 0, 0);
    __syncthreads();
  }
  // epilogue: D[row=m=quad*4+r (+16*mt)][col=n=l15 (+16*nt +64*wave)]
  #pragma unroll
  for (int nt = 0; nt < 4; ++nt) {
    const int n = wave*64 + nt*16 + l15;
    const float bias = b_ih[n] + b_hh[n];
    #pragma unroll
    for (int mt = 0; mt < 4; ++mt) {
      #pragma unroll
      for (int r = 0; r < 4; ++r) {
        size_t m = (size_t)(m0 + mt*16 + quad*4 + r);
        xp[m * HID + n] = f2bf(acc[mt][nt][r] + bias);
      }
    }
  }
}

// ---------------- kernel 2: sequential scan. 16 blocks x 512 thr (8 waves).
// Block g owns batches [16g,16g+16). Wave w owns hidden cols [32w,32w+32) (2 n-tiles).
// W_hh^T held as bf16 B-fragments in registers (64 VGPRs). h double-buffered in LDS.
__global__ __launch_bounds__(512) void rnn_scan(const float* __restrict__ W_hh,
    const unsigned short* __restrict__ xp, float* __restrict__ hT)
{
  __shared__ unsigned short hbuf[2][16][264];   // [buf][batch][hid], +8 pad
  const int tid  = threadIdx.x;
  const int wave = tid >> 6;
  const int lane = tid & 63;
  const int l15  = lane & 15;
  const int quad = lane >> 4;
  const int g = blockIdx.x;
  const int ncol0 = wave * 32;
  const int brow = quad * 4;

  // B fragments: B[k=quad*8+j][n=l15] = W_hh[n][k]  (h @ W_hh^T)
  bf16x8 wf[2][8];
  #pragma unroll
  for (int nt = 0; nt < 2; ++nt) {
    const int n = ncol0 + nt*16 + l15;
    #pragma unroll
    for (int kc = 0; kc < 8; ++kc) {
      const float* src = W_hh + n*HID + kc*32 + quad*8;
      float4 p0 = *(const float4*)src;
      float4 p1 = *(const float4*)(src + 4);
      union { unsigned short u[8]; bf16x8 vec; } t;
      t.u[0]=f2bf(p0.x); t.u[1]=f2bf(p0.y); t.u[2]=f2bf(p0.z); t.u[3]=f2bf(p0.w);
      t.u[4]=f2bf(p1.x); t.u[5]=f2bf(p1.y); t.u[6]=f2bf(p1.z); t.u[7]=f2bf(p1.w);
      wf[nt][kc] = t.vec;
    }
  }
  // zero h buffer 0 (h0 = 0); ws is poisoned 0xAA so must init
  {
    unsigned short* p = &hbuf[0][0][0];
    for (int i = tid; i < 16*264; i += 512) p[i] = 0;
  }
  // prefetch xp for t=0
  unsigned short xpr[2][4], xnx[2][4];
  #pragma unroll
  for (int nt = 0; nt < 2; ++nt)
    #pragma unroll
    for (int r = 0; r < 4; ++r)
      xpr[nt][r] = xp[(size_t)(g*16 + brow + r) * HID + (ncol0 + nt*16 + l15)];
  __syncthreads();

  for (int t = 0; t < SEQ; ++t) {
    const int cur = t & 1;
    // A fragments: A[m=l15 (batch)][k=quad*8+j]
    bf16x8 afr[8];
    #pragma unroll
    for (int kc = 0; kc < 8; ++kc)
      afr[kc] = *(const bf16x8*)&hbuf[cur][l15][kc*32 + quad*8];
    // prefetch next step's xp (hidden under MFMA chain)
    if (t < SEQ-1) {
      #pragma unroll
      for (int nt = 0; nt < 2; ++nt)
        #pragma unroll
        for (int r = 0; r < 4; ++r)
          xnx[nt][r] = xp[((size_t)(t+1)*BATCH + g*16 + brow + r) * HID + (ncol0 + nt*16 + l15)];
    }
    f32x4 acc[2];
    acc[0] = (f32x4){0.f,0.f,0.f,0.f};
    acc[1] = (f32x4){0.f,0.f,0.f,0.f};
    #pragma unroll
    for (int kc = 0; kc < 8; ++kc) {
      acc[0] = __builtin_amdgcn_mfma_f32_16x16x32_bf16(afr[kc], wf[0][kc], acc[0], 0, 0, 0);
      acc[1] = __builtin_amdgcn_mfma_f32_16x16x32_bf16(afr[kc], wf[1][kc], acc[1], 0, 0, 0);
    }
    // combine: D[row=batch brow+r][col=hidden ncol0+nt*16+l15]
    #pragma unroll
    for (int nt = 0; nt < 2; ++nt) {
      #pragma unroll
      for (int r = 0; r < 4; ++r) {
        float pre = acc[nt][r] + bf2f(xpr[nt][r]);
        float cx = fminf(8.f, fmaxf(-8.f, pre));
        float e = __expf(2.f * cx);
        float hv = 1.f - 2.f * __builtin_amdgcn_rcpf(e + 1.f);  // tanh, ~1e-6 rel
        if (t < SEQ-1)
          hbuf[1-cur][brow + r][ncol0 + nt*16 + l15] = f2bf(hv);
        else
          hT[(size_t)(g*16 + brow + r) * HID + (ncol0 + nt*16 + l15)] = hv;
      }
    }
    #pragma unroll
    for (int nt = 0; nt < 2; ++nt)
      #pragma unroll
      for (int r = 0; r < 4; ++r) xpr[nt][r] = xnx[nt][r];
    __syncthreads();   // writes to hbuf[1-cur] visible; t's reads of hbuf[cur] done
  }
}

// ---------------- kernel 3: logits = hT @ W_fc^T + b_fc; log_softmax. 1 wave/batch.
__global__ __launch_bounds__(64) void fc_head(const float* __restrict__ hT,
    const float* __restrict__ W_fc, const float* __restrict__ b_fc,
    float* __restrict__ out)
{
  const int b = blockIdx.x;
  const int l = threadIdx.x;
  float s0 = 0.f, s1 = 0.f;
  #pragma unroll
  for (int j0 = 0; j0 < HID; j0 += 64) {
    float h = hT[(size_t)b * HID + j0 + l];
    s0 += h * W_fc[j0 + l];
    s1 += h * W_fc[HID + j0 + l];
  }
  #pragma unroll
  for (int off = 32; off > 0; off >>= 1) {
    s0 += __shfl_xor(s0, off, 64);
    s1 += __shfl_xor(s1, off, 64);
  }
  if (l == 0) {
    float l0 = s0 + b_fc[0], l1 = s1 + b_fc[1];
    float m = fmaxf(l0, l1);
    float lse = m + logf(expf(l0 - m) + expf(l1 - m));
    out[b*2 + 0] = l0 - lse;
    out[b*2 + 1] = l1 - lse;
  }
}

extern "C" void kernel_launch(void* const* d_in, const int* in_sizes, int n_in,
                              void* d_out, int out_size, void* d_ws, size_t ws_size,
                              hipStream_t stream) {
  const float* x    = (const float*)d_in[0];
  const float* W_ih = (const float*)d_in[1];
  const float* W_hh = (const float*)d_in[2];
  const float* b_ih = (const float*)d_in[3];
  const float* b_hh = (const float*)d_in[4];
  const float* W_fc = (const float*)d_in[5];
  const float* b_fc = (const float*)d_in[6];
  float* out = (float*)d_out;

  const size_t xp_bytes  = (size_t)SEQ * BATCH * HID * 2;   // 67,108,864
  const size_t wb_bytes  = (size_t)256 * 320 * 2;           // 163,840
  const size_t ht_bytes  = (size_t)BATCH * HID * 4;         // 262,144
  if (ws_size < xp_bytes + wb_bytes + ht_bytes) return;     // fail visibly, no UB

  char* ws = (char*)d_ws;
  unsigned short* xp   = (unsigned short*)ws;
  unsigned short* w_bf = (unsigned short*)(ws + xp_bytes);
  float*          hT   = (float*)(ws + xp_bytes + wb_bytes);

  hipLaunchKernelGGL(conv_wih, dim3(320),  dim3(256), 0, stream, W_ih, w_bf);
  hipLaunchKernelGGL(gemm_xp,  dim3(2048), dim3(256), 0, stream, x, w_bf, b_ih, b_hh, xp);
  hipLaunchKernelGGL(rnn_scan, dim3(16),   dim3(512), 0, stream, W_hh, xp, hT);
  hipLaunchKernelGGL(fc_head,  dim3(BATCH), dim3(64), 0, stream, hT, W_fc, b_fc, out);
}

// Round 2
// 632.921 us; speedup vs baseline: 1.0152x; 1.0152x over previous
//
#include <hip/hip_runtime.h>
#include <cstdint>
#include <cstddef>

#define SEQ 512
#define BATCH 256
#define IN_DIM 300
#define HID 256

typedef __attribute__((ext_vector_type(8))) short bf16x8;
typedef __attribute__((ext_vector_type(4))) float f32x4;

__device__ __forceinline__ unsigned short f2bf(float f) {
  union { float f; unsigned int u; } v; v.f = f;
  unsigned int u = v.u;
  return (unsigned short)((u + 0x7fffu + ((u >> 16) & 1u)) >> 16);  // RNE
}
__device__ __forceinline__ unsigned short f2bf_fast(float f) {
  union { float f; unsigned int u; } v; v.f = f;
  return (unsigned short)((v.u + 0x8000u) >> 16);  // round-half-up, err <= 2^-9 rel
}
__device__ __forceinline__ float bf2f(unsigned short s) {
  union { unsigned int u; float f; } v; v.u = ((unsigned int)s) << 16;
  return v.f;
}

// ---------------- kernel 0: W_ih fp32 -> bf16, padded [256][320] (zeros past 300)
__global__ __launch_bounds__(256) void conv_wih(const float* __restrict__ w,
                                                unsigned short* __restrict__ w_bf) {
  int idx = blockIdx.x * 256 + threadIdx.x;   // 0 .. 256*320-1
  int n = idx / 320, k = idx - n * 320;
  float v = (k < IN_DIM) ? w[n * IN_DIM + k] : 0.f;
  w_bf[idx] = f2bf(v);
}

// ---------------- kernel 1: xp[m][n] = 2*(sum_k x[m][k]*W_ih[n][k] + b_ih[n]+b_hh[n]), bf16
// (pre-scaled by 2 so the scan's tanh argument needs one fma only)
__global__ __launch_bounds__(256) void gemm_xp(const float* __restrict__ x,
    const unsigned short* __restrict__ w_bf, const float* __restrict__ b_ih,
    const float* __restrict__ b_hh, unsigned short* __restrict__ xp)
{
  __shared__ unsigned short a_lds[64][40];    // +8 pad
  __shared__ unsigned short w_lds[256][40];
  const int tid  = threadIdx.x;
  const int wave = tid >> 6;
  const int lane = tid & 63;
  const int l15  = lane & 15;
  const int quad = lane >> 4;
  const long m0 = (long)blockIdx.x * 64;

  f32x4 acc[4][4];
  #pragma unroll
  for (int mt = 0; mt < 4; ++mt)
    #pragma unroll
    for (int nt = 0; nt < 4; ++nt) acc[mt][nt] = (f32x4){0.f, 0.f, 0.f, 0.f};

  const int ar = tid >> 2;          // 0..63 row
  const int ac = (tid & 3) * 8;     // 0,8,16,24

  for (int kc = 0; kc < 10; ++kc) {
    const int k0 = kc * 32;
    {
      float v[8];
      const float* src = x + (size_t)(m0 + ar) * IN_DIM + (k0 + ac);
      if (k0 + ac + 8 <= IN_DIM) {
        float2 p0 = *(const float2*)(src + 0);
        float2 p1 = *(const float2*)(src + 2);
        float2 p2 = *(const float2*)(src + 4);
        float2 p3 = *(const float2*)(src + 6);
        v[0]=p0.x; v[1]=p0.y; v[2]=p1.x; v[3]=p1.y;
        v[4]=p2.x; v[5]=p2.y; v[6]=p3.x; v[7]=p3.y;
      } else {
        #pragma unroll
        for (int j = 0; j < 8; ++j) v[j] = (k0 + ac + j < IN_DIM) ? src[j] : 0.f;
      }
      union { unsigned short u[8]; bf16x8 vec; } tmp;
      #pragma unroll
      for (int j = 0; j < 8; ++j) tmp.u[j] = f2bf(v[j]);
      *(bf16x8*)&a_lds[ar][ac] = tmp.vec;
    }
    #pragma unroll
    for (int i = 0; i < 8; ++i) {
      int e = tid + i * 256;
      int n = e >> 3;
      int kk = (e & 7) * 4;
      uint2 d = *(const uint2*)(w_bf + n * 320 + k0 + kk);
      *(uint2*)&w_lds[n][kk] = d;
    }
    __syncthreads();
    bf16x8 afr[4], bfr[4];
    #pragma unroll
    for (int mt = 0; mt < 4; ++mt)
      afr[mt] = *(const bf16x8*)&a_lds[mt*16 + l15][quad*8];
    #pragma unroll
    for (int nt = 0; nt < 4; ++nt)
      bfr[nt] = *(const bf16x8*)&w_lds[wave*64 + nt*16 + l15][quad*8];
    #pragma unroll
    for (int mt = 0; mt < 4; ++mt)
      #pragma unroll
      for (int nt = 0; nt < 4; ++nt)
        acc[mt][nt] = __builtin_amdgcn_mfma_f32_16x16x32_bf16(afr[mt], bfr[nt], acc[mt][nt], 0, 0, 0);
    __syncthreads();
  }
  #pragma unroll
  for (int nt = 0; nt < 4; ++nt) {
    const int n = wave*64 + nt*16 + l15;
    const float kb = 2.0f * (b_ih[n] + b_hh[n]);
    #pragma unroll
    for (int mt = 0; mt < 4; ++mt) {
      #pragma unroll
      for (int r = 0; r < 4; ++r) {
        size_t m = (size_t)(m0 + mt*16 + quad*4 + r);
        xp[m * HID + n] = f2bf(fmaf(2.0f, acc[mt][nt][r], kb));
      }
    }
  }
}

// ---------------- kernel 2: sequential scan. 32 blocks x 512 thr (8 waves).
// Block g owns batches [8g, 8g+8). Wave w owns hidden cols [32w, 32w+32) (2 n-tiles).
// W_hh^T held as bf16 B-fragments in registers. h (8 rows) double-buffered in LDS
// with XOR bank swizzle; A-frag reads row-wrap (l15&7) for broadcast dedup.
// After MFMA, acc[1]'s valid rows (lanes 0-31) are shfl'd to lanes 32-63 so all
// 64 lanes do useful epilogue work (4 slots/lane instead of 8 half-wasted).
__device__ __forceinline__ int swz(int row, int col) {
  return row * 256 + (col ^ ((row & 3) << 3));
}

__global__ __launch_bounds__(512) void rnn_scan(const float* __restrict__ W_hh,
    const unsigned short* __restrict__ xp, float* __restrict__ hT)
{
  __shared__ unsigned short hbuf[2][8 * 256];
  const int tid  = threadIdx.x;
  const int wave = tid >> 6;
  const int lane = tid & 63;
  const int l15  = lane & 15;
  const int quad = lane >> 4;
  const int g = blockIdx.x;
  const int c0 = wave * 32;

  // B fragments: B[k=quad*8+j][n=l15] = W_hh[n][k]
  bf16x8 wf[2][8];
  #pragma unroll
  for (int nt = 0; nt < 2; ++nt) {
    const int n = c0 + nt*16 + l15;
    #pragma unroll
    for (int kc = 0; kc < 8; ++kc) {
      const float* src = W_hh + n*HID + kc*32 + quad*8;
      float4 p0 = *(const float4*)src;
      float4 p1 = *(const float4*)(src + 4);
      union { unsigned short u[8]; bf16x8 vec; } t;
      t.u[0]=f2bf(p0.x); t.u[1]=f2bf(p0.y); t.u[2]=f2bf(p0.z); t.u[3]=f2bf(p0.w);
      t.u[4]=f2bf(p1.x); t.u[5]=f2bf(p1.y); t.u[6]=f2bf(p1.z); t.u[7]=f2bf(p1.w);
      wf[nt][kc] = t.vec;
    }
  }

  // epilogue lane mapping: lanes 0-31 -> n-tile 0, lanes 32-63 -> n-tile 1
  const int myrow = (quad & 1) * 4;                 // + r  (0..7)
  const int mycol = c0 + ((lane >> 5) << 4) + l15;  // hidden col
  const int b = g * 8 + myrow;                      // + r  batch row

  // zero h(0) in buffer 0 (LDS starts poisoned)
  for (int i = tid; i < 8 * 256; i += 512) hbuf[0][i] = 0;

  // prefetch xp for t=0 (4 values: rows b..b+3, col mycol)
  unsigned short xpr[4], xnx[4];
  #pragma unroll
  for (int r = 0; r < 4; ++r)
    xpr[r] = xp[(size_t)(b + r) * HID + mycol];
  __syncthreads();

  for (int t = 0; t < SEQ; ++t) {
    const int cur = t & 1;
    // A fragments: A[m=l15&7 (batch, wrapped)][k=quad*8+j], XOR-swizzled cols
    bf16x8 afr[8];
    #pragma unroll
    for (int kc = 0; kc < 8; ++kc)
      afr[kc] = *(const bf16x8*)&hbuf[cur][swz(l15 & 7, kc*32 + quad*8)];
    // prefetch next step's xp
    if (t < SEQ - 1) {
      #pragma unroll
      for (int r = 0; r < 4; ++r)
        xnx[r] = xp[((size_t)(t + 1) * BATCH + b + r) * HID + mycol];
    }
    f32x4 acc0 = (f32x4){0.f,0.f,0.f,0.f};
    f32x4 acc1 = (f32x4){0.f,0.f,0.f,0.f};
    #pragma unroll
    for (int kc = 0; kc < 8; ++kc) {
      acc0 = __builtin_amdgcn_mfma_f32_16x16x32_bf16(afr[kc], wf[0][kc], acc0, 0, 0, 0);
      acc1 = __builtin_amdgcn_mfma_f32_16x16x32_bf16(afr[kc], wf[1][kc], acc1, 0, 0, 0);
    }
    // remap: lanes >=32 take acc1's valid rows (held in lanes 0..31)
    #pragma unroll
    for (int r = 0; r < 4; ++r) {
      float mv  = __shfl(acc1[r], lane & 31, 64);
      float sel = (lane < 32) ? acc0[r] : mv;
      float y   = fmaf(2.0f, sel, bf2f(xpr[r]));      // 2*(h@W^T + x + b)
      float e   = __expf(y);                          // e^{2 pre}
      float hv  = fmaf(-2.0f, __builtin_amdgcn_rcpf(e + 1.0f), 1.0f);  // tanh
      if (t < SEQ - 1)
        hbuf[1 - cur][swz(myrow + r, mycol)] = f2bf_fast(hv);
      else
        hT[(size_t)(b + r) * HID + mycol] = hv;
      xpr[r] = xnx[r];
    }
    __syncthreads();
  }
}

// ---------------- kernel 3: logits = hT @ W_fc^T + b_fc; log_softmax. 1 wave/batch.
__global__ __launch_bounds__(64) void fc_head(const float* __restrict__ hT,
    const float* __restrict__ W_fc, const float* __restrict__ b_fc,
    float* __restrict__ out)
{
  const int b = blockIdx.x;
  const int l = threadIdx.x;
  float s0 = 0.f, s1 = 0.f;
  #pragma unroll
  for (int j0 = 0; j0 < HID; j0 += 64) {
    float h = hT[(size_t)b * HID + j0 + l];
    s0 += h * W_fc[j0 + l];
    s1 += h * W_fc[HID + j0 + l];
  }
  #pragma unroll
  for (int off = 32; off > 0; off >>= 1) {
    s0 += __shfl_xor(s0, off, 64);
    s1 += __shfl_xor(s1, off, 64);
  }
  if (l == 0) {
    float l0 = s0 + b_fc[0], l1 = s1 + b_fc[1];
    float m = fmaxf(l0, l1);
    float lse = m + logf(expf(l0 - m) + expf(l1 - m));
    out[b*2 + 0] = l0 - lse;
    out[b*2 + 1] = l1 - lse;
  }
}

extern "C" void kernel_launch(void* const* d_in, const int* in_sizes, int n_in,
                              void* d_out, int out_size, void* d_ws, size_t ws_size,
                              hipStream_t stream) {
  const float* x    = (const float*)d_in[0];
  const float* W_ih = (const float*)d_in[1];
  const float* W_hh = (const float*)d_in[2];
  const float* b_ih = (const float*)d_in[3];
  const float* b_hh = (const float*)d_in[4];
  const float* W_fc = (const float*)d_in[5];
  const float* b_fc = (const float*)d_in[6];
  float* out = (float*)d_out;

  const size_t xp_bytes  = (size_t)SEQ * BATCH * HID * 2;   // 67,108,864
  const size_t wb_bytes  = (size_t)256 * 320 * 2;           // 163,840
  const size_t ht_bytes  = (size_t)BATCH * HID * 4;         // 262,144
  if (ws_size < xp_bytes + wb_bytes + ht_bytes) return;

  char* ws = (char*)d_ws;
  unsigned short* xp   = (unsigned short*)ws;
  unsigned short* w_bf = (unsigned short*)(ws + xp_bytes);
  float*          hT   = (float*)(ws + xp_bytes + wb_bytes);

  hipLaunchKernelGGL(conv_wih, dim3(320),  dim3(256), 0, stream, W_ih, w_bf);
  hipLaunchKernelGGL(gemm_xp,  dim3(2048), dim3(256), 0, stream, x, w_bf, b_ih, b_hh, xp);
  hipLaunchKernelGGL(rnn_scan, dim3(32),   dim3(512), 0, stream, W_hh, xp, hT);
  hipLaunchKernelGGL(fc_head,  dim3(BATCH), dim3(64), 0, stream, hT, W_fc, b_fc, out);
}

// Round 3
// 519.070 us; speedup vs baseline: 1.2379x; 1.2193x over previous
//
#include <hip/hip_runtime.h>
#include <hip/hip_bf16.h>
#include <cstdint>
#include <cstddef>

#define SEQ 512
#define BATCH 256
#define IN_DIM 300
#define HID 256

typedef __attribute__((ext_vector_type(8))) short bf16x8;
typedef __attribute__((ext_vector_type(4))) float f32x4;

__device__ __forceinline__ unsigned short f2bf(float f) {
  union { float f; unsigned int u; } v; v.f = f;
  unsigned int u = v.u;
  return (unsigned short)((u + 0x7fffu + ((u >> 16) & 1u)) >> 16);  // RNE
}
__device__ __forceinline__ unsigned short f2bf_fast(float f) {
  union { float f; unsigned int u; } v; v.f = f;
  return (unsigned short)((v.u + 0x8000u) >> 16);  // round-half-up, err <= 2^-9 rel
}
__device__ __forceinline__ float bitsf(unsigned int u) {
  union { unsigned int u; float f; } v; v.u = u; return v.f;
}
__device__ __forceinline__ bf16x8 cvt8(float a0,float a1,float a2,float a3,
                                       float a4,float a5,float a6,float a7) {
  union { __hip_bfloat162 h2[4]; bf16x8 v; } c;
  c.h2[0] = __float22bfloat162_rn(make_float2(a0, a1));
  c.h2[1] = __float22bfloat162_rn(make_float2(a2, a3));
  c.h2[2] = __float22bfloat162_rn(make_float2(a4, a5));
  c.h2[3] = __float22bfloat162_rn(make_float2(a6, a7));
  return c.v;
}

// ---------------- kernel 0: W_ih fp32 -> bf16, padded [256][320]
__global__ __launch_bounds__(256) void conv_wih(const float* __restrict__ w,
                                                unsigned short* __restrict__ w_bf) {
  int idx = blockIdx.x * 256 + threadIdx.x;
  int n = idx / 320, k = idx - n * 320;
  float v = (k < IN_DIM) ? w[n * IN_DIM + k] : 0.f;
  w_bf[idx] = f2bf(v);
}

// ---------------- kernel 1: xp2 (permuted, bf16) = 2*(x@W_ih^T + b_ih + b_hh)
// Permuted layout matches the scan's per-thread consumption:
//   value (t, b, n) -> xp2[ ((t*32 + g)*512 + tid_s)*4 + r ]
//   g = b>>3, r = b&3, tid_s = (n>>5)*64 + ((n>>4)&1)*32 + (((b>>2)&1))*16 + (n&15)
// so each scan thread's step-t quad (r=0..3) is one aligned 8B uint2.
__global__ __launch_bounds__(256) void gemm_xp(const float* __restrict__ x,
    const unsigned short* __restrict__ w_bf, const float* __restrict__ b_ih,
    const float* __restrict__ b_hh, unsigned short* __restrict__ xp2)
{
  __shared__ unsigned short a_lds[64][40];    // +8 pad: rows staggered 4 banks
  __shared__ unsigned short w_lds[256][40];
  const int tid  = threadIdx.x;
  const int wave = tid >> 6;
  const int lane = tid & 63;
  const int l15  = lane & 15;
  const int quad = lane >> 4;
  const long m0 = (long)blockIdx.x * 64;

  f32x4 acc[4][4];
  #pragma unroll
  for (int mt = 0; mt < 4; ++mt)
    #pragma unroll
    for (int nt = 0; nt < 4; ++nt) acc[mt][nt] = (f32x4){0.f, 0.f, 0.f, 0.f};

  const int ar = tid >> 2;          // staging row 0..63
  const int ac = (tid & 3) * 8;     // staging k-offset

  for (int kc = 0; kc < 10; ++kc) {
    const int k0 = kc * 32;
    {
      float v[8];
      const float* src = x + (size_t)(m0 + ar) * IN_DIM + (k0 + ac);
      if (k0 + ac + 8 <= IN_DIM) {
        float2 p0 = *(const float2*)(src + 0);
        float2 p1 = *(const float2*)(src + 2);
        float2 p2 = *(const float2*)(src + 4);
        float2 p3 = *(const float2*)(src + 6);
        v[0]=p0.x; v[1]=p0.y; v[2]=p1.x; v[3]=p1.y;
        v[4]=p2.x; v[5]=p2.y; v[6]=p3.x; v[7]=p3.y;
      } else {
        #pragma unroll
        for (int j = 0; j < 8; ++j) v[j] = (k0 + ac + j < IN_DIM) ? src[j] : 0.f;
      }
      *(bf16x8*)&a_lds[ar][ac] = cvt8(v[0],v[1],v[2],v[3],v[4],v[5],v[6],v[7]);
    }
    #pragma unroll
    for (int i = 0; i < 8; ++i) {
      int e = tid + i * 256;
      int n = e >> 3;
      int kk = (e & 7) * 4;
      uint2 d = *(const uint2*)(w_bf + n * 320 + k0 + kk);
      *(uint2*)&w_lds[n][kk] = d;
    }
    __syncthreads();
    bf16x8 afr[4], bfr[4];
    #pragma unroll
    for (int mt = 0; mt < 4; ++mt)
      afr[mt] = *(const bf16x8*)&a_lds[mt*16 + l15][quad*8];
    #pragma unroll
    for (int nt = 0; nt < 4; ++nt)
      bfr[nt] = *(const bf16x8*)&w_lds[wave*64 + nt*16 + l15][quad*8];
    #pragma unroll
    for (int mt = 0; mt < 4; ++mt)
      #pragma unroll
      for (int nt = 0; nt < 4; ++nt)
        acc[mt][nt] = __builtin_amdgcn_mfma_f32_16x16x32_bf16(afr[mt], bfr[nt], acc[mt][nt], 0, 0, 0);
    __syncthreads();
  }
  // epilogue: t constant per block; pack 4 r-values into one uint2 store
  const int t = (int)(blockIdx.x >> 2);
  #pragma unroll
  for (int nt = 0; nt < 4; ++nt) {
    const int n = wave*64 + nt*16 + l15;
    const float kb = 2.0f * (b_ih[n] + b_hh[n]);
    const int tid_s = (wave*2 + (nt>>1))*64 + (nt&1)*32 + (quad&1)*16 + l15;
    #pragma unroll
    for (int mt = 0; mt < 4; ++mt) {
      const int g = ((int)(blockIdx.x & 3))*8 + mt*2 + (quad>>1);
      float y0 = fmaf(2.0f, acc[mt][nt][0], kb);
      float y1 = fmaf(2.0f, acc[mt][nt][1], kb);
      float y2 = fmaf(2.0f, acc[mt][nt][2], kb);
      float y3 = fmaf(2.0f, acc[mt][nt][3], kb);
      union { __hip_bfloat162 h2[2]; uint2 u; } pk;
      pk.h2[0] = __float22bfloat162_rn(make_float2(y0, y1));
      pk.h2[1] = __float22bfloat162_rn(make_float2(y2, y3));
      *(uint2*)(xp2 + (((size_t)t*32 + g)*512 + tid_s)*4) = pk.u;
    }
  }
}

// ---------------- kernel 2: sequential scan. 32 blocks x 512 thr.
// Block g owns batches [8g, 8g+8). A rows wrapped (l15&7) -> D rows 8-15
// duplicate 0-7, so lanes 32-63 use their own acc1 (no shfl). xp read in
// 16-step register bursts (one vmcnt drain per 16 barriers instead of 1/step).
__global__ __launch_bounds__(512) void rnn_scan(const float* __restrict__ W_hh,
    const unsigned short* __restrict__ xp2, float* __restrict__ hT)
{
  __shared__ unsigned short hbuf[2][8 * 264];   // stride 264: rows staggered 4 banks
  const int tid  = threadIdx.x;
  const int wave = tid >> 6;
  const int lane = tid & 63;
  const int l15  = lane & 15;
  const int quad = lane >> 4;
  const int g = blockIdx.x;
  const int c0 = wave * 32;

  // B fragments: B[k=quad*8+j][n=l15] = W_hh[n][k]
  bf16x8 wf[2][8];
  #pragma unroll
  for (int nt = 0; nt < 2; ++nt) {
    const int n = c0 + nt*16 + l15;
    #pragma unroll
    for (int kc = 0; kc < 8; ++kc) {
      const float* src = W_hh + n*HID + kc*32 + quad*8;
      float4 p0 = *(const float4*)src;
      float4 p1 = *(const float4*)(src + 4);
      wf[nt][kc] = cvt8(p0.x,p0.y,p0.z,p0.w,p1.x,p1.y,p1.z,p1.w);
    }
  }

  const int myrow = ((lane >> 4) & 1) * 4;          // 0 or 4 (+r)
  const int mycol = c0 + ((lane >> 5) << 4) + l15;  // hidden col
  const int b = g * 8 + myrow;

  for (int i = tid; i < 8 * 264; i += 512) hbuf[0][i] = 0;  // h0 = 0

  // burst base: thread's xp2 slot; t stride = 32*512*4 = 65536 shorts
  const unsigned short* xbase = xp2 + (((size_t)g) * 512 + tid) * 4;

  __syncthreads();

  uint2 xq[16];
  for (int tc = 0; tc < SEQ / 16; ++tc) {
    const unsigned short* pb = xbase + (size_t)tc * 16 * 65536;
    #pragma unroll
    for (int j = 0; j < 16; ++j)
      xq[j] = *(const uint2*)(pb + (size_t)j * 65536);
    #pragma unroll
    for (int j = 0; j < 16; ++j) {
      const int t = tc * 16 + j;
      const int cur = j & 1;                        // tc*16 even -> t&1 == j&1
      bf16x8 afr[8];
      #pragma unroll
      for (int kc = 0; kc < 8; ++kc)
        afr[kc] = *(const bf16x8*)&hbuf[cur][(l15 & 7) * 264 + kc*32 + quad*8];
      f32x4 acc0 = (f32x4){0.f,0.f,0.f,0.f};
      f32x4 acc1 = (f32x4){0.f,0.f,0.f,0.f};
      #pragma unroll
      for (int kc = 0; kc < 8; ++kc) {
        acc0 = __builtin_amdgcn_mfma_f32_16x16x32_bf16(afr[kc], wf[0][kc], acc0, 0, 0, 0);
        acc1 = __builtin_amdgcn_mfma_f32_16x16x32_bf16(afr[kc], wf[1][kc], acc1, 0, 0, 0);
      }
      float xv[4];
      xv[0] = bitsf(xq[j].x << 16);
      xv[1] = bitsf(xq[j].x & 0xffff0000u);
      xv[2] = bitsf(xq[j].y << 16);
      xv[3] = bitsf(xq[j].y & 0xffff0000u);
      #pragma unroll
      for (int r = 0; r < 4; ++r) {
        float sel = (lane < 32) ? acc0[r] : acc1[r];
        float y  = fmaf(2.0f, sel, xv[r]);          // 2*(h@W^T + x + b)
        float e  = __expf(y);
        float hv = fmaf(-2.0f, __builtin_amdgcn_rcpf(e + 1.0f), 1.0f);  // tanh
        if (t < SEQ - 1)
          hbuf[1 - cur][(myrow + r) * 264 + mycol] = f2bf_fast(hv);
        else
          hT[(size_t)(b + r) * HID + mycol] = hv;
      }
      __syncthreads();
    }
  }
}

// ---------------- kernel 3: logits + log_softmax. 1 wave/batch.
__global__ __launch_bounds__(64) void fc_head(const float* __restrict__ hT,
    const float* __restrict__ W_fc, const float* __restrict__ b_fc,
    float* __restrict__ out)
{
  const int b = blockIdx.x;
  const int l = threadIdx.x;
  float s0 = 0.f, s1 = 0.f;
  #pragma unroll
  for (int j0 = 0; j0 < HID; j0 += 64) {
    float h = hT[(size_t)b * HID + j0 + l];
    s0 += h * W_fc[j0 + l];
    s1 += h * W_fc[HID + j0 + l];
  }
  #pragma unroll
  for (int off = 32; off > 0; off >>= 1) {
    s0 += __shfl_xor(s0, off, 64);
    s1 += __shfl_xor(s1, off, 64);
  }
  if (l == 0) {
    float l0 = s0 + b_fc[0], l1 = s1 + b_fc[1];
    float m = fmaxf(l0, l1);
    float lse = m + logf(expf(l0 - m) + expf(l1 - m));
    out[b*2 + 0] = l0 - lse;
    out[b*2 + 1] = l1 - lse;
  }
}

extern "C" void kernel_launch(void* const* d_in, const int* in_sizes, int n_in,
                              void* d_out, int out_size, void* d_ws, size_t ws_size,
                              hipStream_t stream) {
  const float* x    = (const float*)d_in[0];
  const float* W_ih = (const float*)d_in[1];
  const float* W_hh = (const float*)d_in[2];
  const float* b_ih = (const float*)d_in[3];
  const float* b_hh = (const float*)d_in[4];
  const float* W_fc = (const float*)d_in[5];
  const float* b_fc = (const float*)d_in[6];
  float* out = (float*)d_out;

  const size_t xp_bytes = (size_t)SEQ * BATCH * HID * 2;   // 67,108,864
  const size_t wb_bytes = (size_t)256 * 320 * 2;
  const size_t ht_bytes = (size_t)BATCH * HID * 4;
  if (ws_size < xp_bytes + wb_bytes + ht_bytes) return;

  char* ws = (char*)d_ws;
  unsigned short* xp2  = (unsigned short*)ws;
  unsigned short* w_bf = (unsigned short*)(ws + xp_bytes);
  float*          hT   = (float*)(ws + xp_bytes + wb_bytes);

  hipLaunchKernelGGL(conv_wih, dim3(320),  dim3(256), 0, stream, W_ih, w_bf);
  hipLaunchKernelGGL(gemm_xp,  dim3(2048), dim3(256), 0, stream, x, w_bf, b_ih, b_hh, xp2);
  hipLaunchKernelGGL(rnn_scan, dim3(32),   dim3(512), 0, stream, W_hh, xp2, hT);
  hipLaunchKernelGGL(fc_head,  dim3(BATCH), dim3(64), 0, stream, hT, W_fc, b_fc, out);
}

// Round 4
// 501.562 us; speedup vs baseline: 1.2811x; 1.0349x over previous
//
#include <hip/hip_runtime.h>
#include <hip/hip_bf16.h>
#include <cstdint>
#include <cstddef>

#define SEQ 512
#define BATCH 256
#define IN_DIM 300
#define HID 256

typedef __attribute__((ext_vector_type(8))) short bf16x8;
typedef __attribute__((ext_vector_type(4))) float f32x4;

__device__ __forceinline__ unsigned short f2bf(float f) {
  union { float f; unsigned int u; } v; v.f = f;
  unsigned int u = v.u;
  return (unsigned short)((u + 0x7fffu + ((u >> 16) & 1u)) >> 16);  // RNE
}
__device__ __forceinline__ unsigned short f2bf_fast(float f) {
  union { float f; unsigned int u; } v; v.f = f;
  return (unsigned short)((v.u + 0x8000u) >> 16);  // round-half-up, err <= 2^-9 rel
}
__device__ __forceinline__ float bitsf(unsigned int u) {
  union { unsigned int u; float f; } v; v.u = u; return v.f;
}
__device__ __forceinline__ bf16x8 cvt8(float a0,float a1,float a2,float a3,
                                       float a4,float a5,float a6,float a7) {
  union { __hip_bfloat162 h2[4]; bf16x8 v; } c;
  c.h2[0] = __float22bfloat162_rn(make_float2(a0, a1));
  c.h2[1] = __float22bfloat162_rn(make_float2(a2, a3));
  c.h2[2] = __float22bfloat162_rn(make_float2(a4, a5));
  c.h2[3] = __float22bfloat162_rn(make_float2(a6, a7));
  return c.v;
}

// ---------------- kernel 0: W_ih fp32 -> bf16, padded [256][320]
__global__ __launch_bounds__(256) void conv_wih(const float* __restrict__ w,
                                                unsigned short* __restrict__ w_bf) {
  int idx = blockIdx.x * 256 + threadIdx.x;
  int n = idx / 320, k = idx - n * 320;
  float v = (k < IN_DIM) ? w[n * IN_DIM + k] : 0.f;
  w_bf[idx] = f2bf(v);
}

// ---------------- kernel 1: xp2 (permuted, bf16) = 2*(x@W_ih^T + b_ih + b_hh)
// Layout matches scan consumption (64 groups of 4 batches):
//   value (t, b, n): g=b>>2, rr=b&3, w_s=n>>5, tid_s = w_s*64 + ((rr>>1)*2+((n>>4)&1))*16 + (n&15)
//   dword index = (t*64+g)*512 + tid_s, low short = rr even, high short = rr odd.
// Staging globals software-pipelined one K-iter ahead (hidden under MFMA).
__global__ __launch_bounds__(256) void gemm_xp(const float* __restrict__ x,
    const unsigned short* __restrict__ w_bf, const float* __restrict__ b_ih,
    const float* __restrict__ b_hh, unsigned int* __restrict__ xp2)
{
  __shared__ unsigned short a_lds[64][40];
  __shared__ unsigned short w_lds[256][40];
  const int tid  = threadIdx.x;
  const int wave = tid >> 6;
  const int lane = tid & 63;
  const int l15  = lane & 15;
  const int quad = lane >> 4;
  const long m0 = (long)blockIdx.x * 64;

  f32x4 acc[4][4];
  #pragma unroll
  for (int mt = 0; mt < 4; ++mt)
    #pragma unroll
    for (int nt = 0; nt < 4; ++nt) acc[mt][nt] = (f32x4){0.f, 0.f, 0.f, 0.f};

  const int ar = tid >> 2;
  const int ac = (tid & 3) * 8;

  float av[8];
  uint2 wv[8];
  // prefetch kc=0
  {
    const float* src = x + (size_t)(m0 + ar) * IN_DIM + ac;
    float2 p0 = *(const float2*)(src + 0);
    float2 p1 = *(const float2*)(src + 2);
    float2 p2 = *(const float2*)(src + 4);
    float2 p3 = *(const float2*)(src + 6);
    av[0]=p0.x; av[1]=p0.y; av[2]=p1.x; av[3]=p1.y;
    av[4]=p2.x; av[5]=p2.y; av[6]=p3.x; av[7]=p3.y;
    #pragma unroll
    for (int i = 0; i < 8; ++i) {
      int e = tid + i * 256;
      wv[i] = *(const uint2*)(w_bf + (e >> 3) * 320 + (e & 7) * 4);
    }
  }

  for (int kc = 0; kc < 10; ++kc) {
    *(bf16x8*)&a_lds[ar][ac] = cvt8(av[0],av[1],av[2],av[3],av[4],av[5],av[6],av[7]);
    #pragma unroll
    for (int i = 0; i < 8; ++i) {
      int e = tid + i * 256;
      *(uint2*)&w_lds[e >> 3][(e & 7) * 4] = wv[i];
    }
    __syncthreads();
    // prefetch kc+1 (overlaps frag reads + MFMA below)
    if (kc < 9) {
      const int k0 = (kc + 1) * 32;
      const float* src = x + (size_t)(m0 + ar) * IN_DIM + (k0 + ac);
      if (k0 + ac + 8 <= IN_DIM) {
        float2 p0 = *(const float2*)(src + 0);
        float2 p1 = *(const float2*)(src + 2);
        float2 p2 = *(const float2*)(src + 4);
        float2 p3 = *(const float2*)(src + 6);
        av[0]=p0.x; av[1]=p0.y; av[2]=p1.x; av[3]=p1.y;
        av[4]=p2.x; av[5]=p2.y; av[6]=p3.x; av[7]=p3.y;
      } else {
        #pragma unroll
        for (int j = 0; j < 8; ++j) av[j] = (k0 + ac + j < IN_DIM) ? src[j] : 0.f;
      }
      #pragma unroll
      for (int i = 0; i < 8; ++i) {
        int e = tid + i * 256;
        wv[i] = *(const uint2*)(w_bf + (e >> 3) * 320 + k0 + (e & 7) * 4);
      }
    }
    bf16x8 afr[4], bfr[4];
    #pragma unroll
    for (int mt = 0; mt < 4; ++mt)
      afr[mt] = *(const bf16x8*)&a_lds[mt*16 + l15][quad*8];
    #pragma unroll
    for (int nt = 0; nt < 4; ++nt)
      bfr[nt] = *(const bf16x8*)&w_lds[wave*64 + nt*16 + l15][quad*8];
    #pragma unroll
    for (int mt = 0; mt < 4; ++mt)
      #pragma unroll
      for (int nt = 0; nt < 4; ++nt)
        acc[mt][nt] = __builtin_amdgcn_mfma_f32_16x16x32_bf16(afr[mt], bfr[nt], acc[mt][nt], 0, 0, 0);
    __syncthreads();
  }
  // epilogue: scatter to scan-permuted layout, packed dword stores
  const int t = (int)(blockIdx.x >> 2);
  #pragma unroll
  for (int nt = 0; nt < 4; ++nt) {
    const int n = wave*64 + nt*16 + l15;
    const float kb = 2.0f * (b_ih[n] + b_hh[n]);
    const int tid_lo = (wave*2 + (nt>>1))*64 + (nt&1)*16 + l15;
    #pragma unroll
    for (int mt = 0; mt < 4; ++mt) {
      const int g = ((int)(blockIdx.x & 3))*16 + mt*4 + quad;
      const size_t base = ((size_t)t*64 + g)*512;
      float y0 = fmaf(2.0f, acc[mt][nt][0], kb);
      float y1 = fmaf(2.0f, acc[mt][nt][1], kb);
      float y2 = fmaf(2.0f, acc[mt][nt][2], kb);
      float y3 = fmaf(2.0f, acc[mt][nt][3], kb);
      union { __hip_bfloat162 h2; unsigned int u; } p01, p23;
      p01.h2 = __float22bfloat162_rn(make_float2(y0, y1));
      p23.h2 = __float22bfloat162_rn(make_float2(y2, y3));
      xp2[base + tid_lo]      = p01.u;
      xp2[base + tid_lo + 32] = p23.u;
    }
  }
}

// ---------------- kernel 2: sequential scan. 64 blocks x 512 thr (8 waves).
// Block g owns batches [4g, 4g+4). Wave w owns hidden cols [32w, 32w+32).
// A rows wrapped (l15&3): D row quad*4+r == batch r for every quad, so all
// lanes hold valid duplicates; quad selects (n-tile, batch-pair) for epilogue.
// LDS stride 272 shorts -> A-frag reads exactly 2-way (free). Dual accumulators
// halve MFMA chain depth. xp in 16-step reg bursts (1 dword/lane/step).
__global__ __launch_bounds__(512) void rnn_scan(const float* __restrict__ W_hh,
    const unsigned int* __restrict__ xp2, float* __restrict__ hT)
{
  __shared__ alignas(16) unsigned short hbuf[2][4 * 272];
  const int tid  = threadIdx.x;
  const int wave = tid >> 6;
  const int lane = tid & 63;
  const int l15  = lane & 15;
  const int quad = lane >> 4;
  const int g = blockIdx.x;
  const int c0 = wave * 32;

  // B fragments: B[k=quad*8+j][n=l15] = W_hh[n][k]
  bf16x8 wf[2][8];
  #pragma unroll
  for (int nt = 0; nt < 2; ++nt) {
    const int n = c0 + nt*16 + l15;
    #pragma unroll
    for (int kc = 0; kc < 8; ++kc) {
      const float* src = W_hh + n*HID + kc*32 + quad*8;
      float4 p0 = *(const float4*)src;
      float4 p1 = *(const float4*)(src + 4);
      wf[nt][kc] = cvt8(p0.x,p0.y,p0.z,p0.w,p1.x,p1.y,p1.z,p1.w);
    }
  }

  const int rb    = (quad >> 1) * 2;                 // batch pair base: rb, rb+1
  const int col_e = c0 + (quad & 1) * 16 + l15;      // epilogue hidden col
  const int abase = (l15 & 3) * 272 + quad * 8;      // A-frag read base

  for (int i = tid; i < 4 * 272; i += 512) hbuf[0][i] = 0;  // h0 = 0

  const unsigned int* xbase = xp2 + (size_t)g * 512 + tid;  // t stride 64*512 dwords

  __syncthreads();

  unsigned int xq[16];
  for (int tc = 0; tc < SEQ / 16; ++tc) {
    const unsigned int* pb = xbase + (size_t)tc * 16 * 32768;
    #pragma unroll
    for (int j = 0; j < 16; ++j)
      xq[j] = pb[(size_t)j * 32768];
    #pragma unroll
    for (int j = 0; j < 16; ++j) {
      const int cur = j & 1;                         // t parity == j parity
      bf16x8 afr[8];
      #pragma unroll
      for (int kc = 0; kc < 8; ++kc)
        afr[kc] = *(const bf16x8*)&hbuf[cur][abase + kc*32];
      f32x4 a0A = (f32x4){0.f,0.f,0.f,0.f}, a0B = a0A, a1A = a0A, a1B = a0A;
      #pragma unroll
      for (int kc = 0; kc < 8; kc += 2) {
        a0A = __builtin_amdgcn_mfma_f32_16x16x32_bf16(afr[kc],   wf[0][kc],   a0A, 0, 0, 0);
        a1A = __builtin_amdgcn_mfma_f32_16x16x32_bf16(afr[kc],   wf[1][kc],   a1A, 0, 0, 0);
        a0B = __builtin_amdgcn_mfma_f32_16x16x32_bf16(afr[kc+1], wf[0][kc+1], a0B, 0, 0, 0);
        a1B = __builtin_amdgcn_mfma_f32_16x16x32_bf16(afr[kc+1], wf[1][kc+1], a1B, 0, 0, 0);
      }
      f32x4 acc0 = a0A + a0B;
      f32x4 acc1 = a1A + a1B;
      // per-lane select: n-tile = quad&1, batch pair = quad>>1
      f32x4 a = (quad & 1) ? acc1 : acc0;
      float s0 = (quad >> 1) ? a[2] : a[0];
      float s1 = (quad >> 1) ? a[3] : a[1];
      float xv0 = bitsf(xq[j] << 16);
      float xv1 = bitsf(xq[j] & 0xffff0000u);
      float y0 = fmaf(2.0f, s0, xv0);
      float y1 = fmaf(2.0f, s1, xv1);
      float h0 = fmaf(-2.0f, __builtin_amdgcn_rcpf(__expf(y0) + 1.0f), 1.0f);
      float h1 = fmaf(-2.0f, __builtin_amdgcn_rcpf(__expf(y1) + 1.0f), 1.0f);
      if (j < 15 || tc < SEQ/16 - 1) {
        hbuf[1 - cur][ rb      * 272 + col_e] = f2bf_fast(h0);
        hbuf[1 - cur][(rb + 1) * 272 + col_e] = f2bf_fast(h1);
      } else {
        hT[(size_t)(g*4 + rb    ) * HID + col_e] = h0;
        hT[(size_t)(g*4 + rb + 1) * HID + col_e] = h1;
      }
      __syncthreads();
    }
  }
}

// ---------------- kernel 3: logits + log_softmax. 1 wave/batch.
__global__ __launch_bounds__(64) void fc_head(const float* __restrict__ hT,
    const float* __restrict__ W_fc, const float* __restrict__ b_fc,
    float* __restrict__ out)
{
  const int b = blockIdx.x;
  const int l = threadIdx.x;
  float s0 = 0.f, s1 = 0.f;
  #pragma unroll
  for (int j0 = 0; j0 < HID; j0 += 64) {
    float h = hT[(size_t)b * HID + j0 + l];
    s0 += h * W_fc[j0 + l];
    s1 += h * W_fc[HID + j0 + l];
  }
  #pragma unroll
  for (int off = 32; off > 0; off >>= 1) {
    s0 += __shfl_xor(s0, off, 64);
    s1 += __shfl_xor(s1, off, 64);
  }
  if (l == 0) {
    float l0 = s0 + b_fc[0], l1 = s1 + b_fc[1];
    float m = fmaxf(l0, l1);
    float lse = m + logf(expf(l0 - m) + expf(l1 - m));
    out[b*2 + 0] = l0 - lse;
    out[b*2 + 1] = l1 - lse;
  }
}

extern "C" void kernel_launch(void* const* d_in, const int* in_sizes, int n_in,
                              void* d_out, int out_size, void* d_ws, size_t ws_size,
                              hipStream_t stream) {
  const float* x    = (const float*)d_in[0];
  const float* W_ih = (const float*)d_in[1];
  const float* W_hh = (const float*)d_in[2];
  const float* b_ih = (const float*)d_in[3];
  const float* b_hh = (const float*)d_in[4];
  const float* W_fc = (const float*)d_in[5];
  const float* b_fc = (const float*)d_in[6];
  float* out = (float*)d_out;

  const size_t xp_bytes = (size_t)SEQ * BATCH * HID * 2;   // 67,108,864
  const size_t wb_bytes = (size_t)256 * 320 * 2;
  const size_t ht_bytes = (size_t)BATCH * HID * 4;
  if (ws_size < xp_bytes + wb_bytes + ht_bytes) return;

  char* ws = (char*)d_ws;
  unsigned int*   xp2  = (unsigned int*)ws;
  unsigned short* w_bf = (unsigned short*)(ws + xp_bytes);
  float*          hT   = (float*)(ws + xp_bytes + wb_bytes);

  hipLaunchKernelGGL(conv_wih, dim3(320),  dim3(256), 0, stream, W_ih, w_bf);
  hipLaunchKernelGGL(gemm_xp,  dim3(2048), dim3(256), 0, stream, x, w_bf, b_ih, b_hh, xp2);
  hipLaunchKernelGGL(rnn_scan, dim3(64),   dim3(512), 0, stream, W_hh, xp2, hT);
  hipLaunchKernelGGL(fc_head,  dim3(BATCH), dim3(64), 0, stream, hT, W_fc, b_fc, out);
}